// Round 16
// baseline (164.789 us; speedup 1.0000x reference)
//
#include <hip/hip_runtime.h>
#include <stdint.h>

typedef __attribute__((ext_vector_type(8))) short bh8;     // 8 bf16 (MFMA A/B frag)
typedef __attribute__((ext_vector_type(4))) float f32x4;
typedef __attribute__((ext_vector_type(16))) float f32x16; // 32x32 MFMA C/D frag
typedef __attribute__((ext_vector_type(2))) __fp16 h16x2;  // packed half2 (native)
typedef unsigned int uint32;

__device__ __forceinline__ unsigned short f2bf(float f) {
  uint32 u = __builtin_bit_cast(uint32, f);
  u += 0x7fffu + ((u >> 16) & 1u);   // RNE
  return (unsigned short)(u >> 16);
}

__device__ __forceinline__ uint32 cvtpk_bf16(float lo, float hi) {
  uint32 r;
  asm("v_cvt_pk_bf16_f32 %0, %1, %2" : "=v"(r) : "v"(lo), "v"(hi));
  return r;
}

__device__ __forceinline__ float exp2_hw(float x) {
  float r;
  asm("v_exp_f32 %0, %1" : "=v"(r) : "v"(x));
  return r;
}

__device__ __forceinline__ float max3f(float a, float b, float c) {
  return fmaxf(fmaxf(a, b), c);   // clang fuses to v_max3_f32
}

// global -> LDS direct (16B/lane). LDS dest linear; swizzle via GLOBAL source addr.
__device__ __forceinline__ void lds_load16(const void* g, void* l) {
  auto gp = (const __attribute__((address_space(1))) uint32*)(uintptr_t)(g);
  auto lp = (__attribute__((address_space(3))) uint32*)(uintptr_t)(l);
  __builtin_amdgcn_global_load_lds(gp, lp, 16, 0, 0);
}

// ---------------------------------------------------------------------------
// Transpose hidden (t,c,p) -> x_bf16[n=t*256+p][c], and W (c,d) -> Wt_bf16[d][c].
// Wq gets 1/sqrt(256) * log2(e) folded in (softmax runs in exp2 domain).
__global__ __launch_bounds__(256) void k_transpose(
    const float* __restrict__ hidden, const float* __restrict__ Wq,
    const float* __restrict__ Wk, const float* __restrict__ Wv,
    unsigned short* __restrict__ xb, unsigned short* __restrict__ wt) {
  int bid = blockIdx.x, c0 = blockIdx.y * 16, tid = threadIdx.x;
  const float* in; unsigned short* out; float scale = 1.0f;
  if (bid < 32) { in = hidden + (size_t)bid * 65536; out = xb + (size_t)bid * 65536; }
  else {
    int j = bid - 32;
    in = (j == 0) ? Wq : (j == 1 ? Wk : Wv);
    out = wt + (size_t)j * 65536;
    if (j == 0) scale = 0.0625f * 1.4426950408889634f;   // 1/sqrt(256) * log2(e)
  }
  __shared__ uint32 lt[256 * 9];
  uint32 pk[8];
#pragma unroll
  for (int i = 0; i < 8; ++i) {
    float a = in[(size_t)(c0 + 2 * i) * 256 + tid] * scale;      // coalesced along p
    float b = in[(size_t)(c0 + 2 * i + 1) * 256 + tid] * scale;
    pk[i] = (uint32)f2bf(a) | ((uint32)f2bf(b) << 16);
  }
#pragma unroll
  for (int i = 0; i < 8; ++i) lt[tid * 9 + i] = pk[i];
  __syncthreads();
  int q2 = tid & 1;
#pragma unroll
  for (int rr = 0; rr < 2; ++rr) {
    int r = rr * 128 + (tid >> 1);
    uint4 v;
    v.x = lt[r * 9 + q2 * 4 + 0]; v.y = lt[r * 9 + q2 * 4 + 1];
    v.z = lt[r * 9 + q2 * 4 + 2]; v.w = lt[r * 9 + q2 * 4 + 3];
    *(uint4*)(out + (size_t)r * 256 + c0 + q2 * 8) = v;          // 16B coalesced
  }
}

// ---------------------------------------------------------------------------
// GEMM: z=0: q = x*WqT_t, z=1: k = x*WkT_t (row-major [n][d]),
//       z=2: vT[d][n] = (WvT * xT)  (operand-swapped so output is d-major).
__global__ __launch_bounds__(256, 2) void k_gemm(
    const unsigned short* __restrict__ xb, const unsigned short* __restrict__ wt,
    unsigned short* __restrict__ qb, unsigned short* __restrict__ kb,
    unsigned short* __restrict__ vtb) {
  __shared__ char lds[32768];
  char* ldsA = lds; char* ldsB = lds + 16384;
  int tid = threadIdx.x, z = blockIdx.z;
  int l = tid & 63, w = tid >> 6, g = l >> 4, r15 = l & 15;
  int wr = w >> 1, wc = w & 1;
  const unsigned short *Ag, *Bg; unsigned short* out;
  int arow0, brow0; size_t ostride;
  if (z < 2) {
    Ag = xb; arow0 = blockIdx.x * 128;
    Bg = wt + (size_t)z * 65536; brow0 = blockIdx.y * 128;
    out = z ? kb : qb; ostride = 256;
  } else {
    Ag = wt + 2 * 65536; arow0 = blockIdx.y * 128;
    Bg = xb; brow0 = blockIdx.x * 128;
    out = vtb; ostride = 8192;
  }
  f32x4 acc[4][4];
#pragma unroll
  for (int i = 0; i < 4; ++i)
#pragma unroll
    for (int j = 0; j < 4; ++j) acc[i][j] = (f32x4){0.f, 0.f, 0.f, 0.f};

  for (int kk = 0; kk < 4; ++kk) {
    int c0 = kk * 64;
    __syncthreads();
#pragma unroll
    for (int p = 0; p < 4; ++p) {     // A tile [128][64] bf16, swizzled chunks
      int off = p * 4096 + tid * 16;
      int row = off >> 7, ch = (off >> 4) & 7, sc = ch ^ (row & 7);
      lds_load16((const char*)Ag + ((size_t)(arow0 + row) * 256 + c0) * 2 + sc * 16, ldsA + off);
    }
#pragma unroll
    for (int p = 0; p < 4; ++p) {     // B tile [128][64] bf16 (col-major tile), swizzled
      int off = p * 4096 + tid * 16;
      int row = off >> 7, ch = (off >> 4) & 7, sc = ch ^ (row & 7);
      lds_load16((const char*)Bg + ((size_t)(brow0 + row) * 256 + c0) * 2 + sc * 16, ldsB + off);
    }
    __syncthreads();
#pragma unroll
    for (int ks = 0; ks < 2; ++ks) {
      bh8 af[4], bfr[4];
#pragma unroll
      for (int i = 0; i < 4; ++i) {
        int rowa = wr * 64 + i * 16 + r15;
        af[i] = *(const bh8*)(ldsA + rowa * 128 + (((ks * 4 + g) ^ (rowa & 7)) * 16));
        int rowb = wc * 64 + i * 16 + r15;
        bfr[i] = *(const bh8*)(ldsB + rowb * 128 + (((ks * 4 + g) ^ (rowb & 7)) * 16));
      }
#pragma unroll
      for (int i = 0; i < 4; ++i)
#pragma unroll
        for (int j = 0; j < 4; ++j)
          acc[i][j] = __builtin_amdgcn_mfma_f32_16x16x32_bf16(af[i], bfr[j], acc[i][j], 0, 0, 0);
    }
  }
  __syncthreads();
  // bounce C (bf16) through LDS for coalesced stores
#pragma unroll
  for (int i = 0; i < 4; ++i)
#pragma unroll
    for (int j = 0; j < 4; ++j)
#pragma unroll
      for (int r = 0; r < 4; ++r) {
        int rowl = wr * 64 + i * 16 + g * 4 + r;   // C/D: row=(l>>4)*4+reg
        int coll = wc * 64 + j * 16 + r15;         //      col=l&15
        *(unsigned short*)(lds + rowl * 256 + coll * 2) = f2bf(acc[i][j][r]);
      }
  __syncthreads();
#pragma unroll
  for (int p = 0; p < 8; ++p) {
    int off = p * 4096 + tid * 16;
    int row = off >> 8, colb = off & 255;
    *(uint4*)((char*)out + ((size_t)(arow0 + row) * ostride + (size_t)brow0) * 2 + colb) =
        *(const uint4*)(lds + off);
  }
}

// ---------------------------------------------------------------------------
// Flash attention, swapped-QK^T 32x32x16. ONE 512-thread block per CU:
// 8 waves x 32 q-rows (QBLK=256), KVBLK=64.
// r16: DEFERRED PV. Per tile kt, the merged loop interleaves QK(kt)'s two
// dependent 16-chains with PV(kt-1)'s 32 INDEPENDENT MFMAs + vf reads (pa held
// in regs across tiles). PV fills QK chain-latency bubbles; softmax(kt) then
// runs with PV(kt-1) retired, and its defer-max rescale of o stays consistent
// (PV added before rescale; pa built under one combined m). Buffers: K double
// (2x32KB) + V TRIPLE (3x32KB) = 160KB LDS exactly, so stage(kt+1) never
// collides with PV(kt-1)'s V reads. One barrier/tile; vmcnt(0) free (loads
// issued a full tile earlier).
// K tile [64][512B], VT tile [256][128B], 16B-chunk XOR swizzle (^ row&7).
// S=8 XCD-pinned slices (bid&7), grid 256 = 1 block/CU.
__global__ __launch_bounds__(512, 2) void k_attn(
    const unsigned short* __restrict__ qg, const unsigned short* __restrict__ kg,
    const unsigned short* __restrict__ vtg, uint32* __restrict__ Op,
    float* __restrict__ mp, float* __restrict__ lp, int S, int shift, int KS) {
  extern __shared__ char smem[];
  int tid = threadIdx.x;
  int w = tid >> 6, l = tid & 63, col = l & 31, half = l >> 5;
  int bid = blockIdx.x;
  int s = bid & (S - 1);       // XCD-pinned slice
  int qb = bid >> shift;
  int qrow0 = qb * 256 + w * 32;

  int nt = KS >> 6, kb0 = s * KS;

  char* Kb0 = smem;
  char* Kb1 = smem + 32768;
  char* Vp = smem + 65536 + 2 * 32768;   // rotates; unused value at tile 0
  char* Vc = smem + 65536;
  char* Vn = smem + 65536 + 32768;

  auto stageK = [&](char* Kd, int kvb) {
#pragma unroll
    for (int p = 0; p < 4; ++p) {
      int off = p * 8192 + tid * 16;
      int row = off >> 9, ch = (off >> 4) & 31;
      lds_load16((const char*)kg + (size_t)(kvb + row) * 512 + ((ch ^ (row & 7)) * 16), Kd + off);
    }
  };
  auto stageV = [&](char* Vd, int kvb) {
#pragma unroll
    for (int p = 0; p < 4; ++p) {
      int off = p * 8192 + tid * 16;
      int row = off >> 7, ch = (off >> 4) & 7;
      lds_load16((const char*)vtg + (size_t)row * 16384 + (size_t)kvb * 2 + ((ch ^ (row & 7)) * 16),
                 Vd + off);
    }
  };

  stageK(Kb0, kb0);
  stageV(Vc, kb0);

  // Q hoisted as B-fragments: lane's q-row = qrow0+col; 16 d-slices x 8 bf16
  bh8 qf[16];
  {
    const char* qrow = (const char*)qg + (size_t)(qrow0 + col) * 512 + half * 16;
#pragma unroll
    for (int t = 0; t < 16; ++t) qf[t] = *(const bh8*)(qrow + t * 32);
  }

  f32x16 o[8];
#pragma unroll
  for (int dt = 0; dt < 8; ++dt)
#pragma unroll
    for (int i = 0; i < 16; ++i) o[dt][i] = 0.f;
  float m = -INFINITY, ls = 0.f;
  bh8 pa[4];
  int r0 = col, r1 = 32 + col;

  // combined softmax over both halves (exp2 domain, defer-max) -> pa
  auto softmax_pa = [&](f32x16& sc0, f32x16& sc1) {
    float t0 = max3f(sc0[0], sc0[1], sc0[2]);
    float t1 = max3f(sc0[3], sc0[4], sc0[5]);
    float t2 = max3f(sc0[6], sc0[7], sc0[8]);
    float t3 = max3f(sc0[9], sc0[10], sc0[11]);
    float t4 = max3f(sc0[12], sc0[13], sc0[14]);
    float rm0 = fmaxf(max3f(t0, t1, t2), max3f(t3, t4, sc0[15]));
    float u0 = max3f(sc1[0], sc1[1], sc1[2]);
    float u1 = max3f(sc1[3], sc1[4], sc1[5]);
    float u2 = max3f(sc1[6], sc1[7], sc1[8]);
    float u3 = max3f(sc1[9], sc1[10], sc1[11]);
    float u4 = max3f(sc1[12], sc1[13], sc1[14]);
    float rm1 = fmaxf(max3f(u0, u1, u2), max3f(u3, u4, sc1[15]));
    float rm = fmaxf(rm0, rm1);
    rm = fmaxf(rm, __shfl_xor(rm, 32));

    if (__any(rm > m + 6.0f)) {      // rare (T13 defer-max)
      float mn = fmaxf(m, rm);
      float scl = exp2_hw(m - mn);
      m = mn;
      float sclb[16];
#pragma unroll
      for (int i = 0; i < 16; ++i) {
        int qs = (i & 3) + 8 * (i >> 2) + 4 * half;   // q-row held in reg i
        sclb[i] = __shfl(scl, qs);
      }
#pragma unroll
      for (int dt = 0; dt < 8; ++dt)
#pragma unroll
        for (int i = 0; i < 16; ++i) o[dt][i] *= sclb[i];
      ls *= scl;
    }
#pragma unroll
    for (int i = 0; i < 16; ++i) sc0[i] = exp2_hw(sc0[i] - m);
#pragma unroll
    for (int i = 0; i < 16; ++i) sc1[i] = exp2_hw(sc1[i] - m);
    float s0 = ((sc0[0] + sc0[1]) + (sc0[2] + sc0[3])) + ((sc0[4] + sc0[5]) + (sc0[6] + sc0[7]));
    float s1 = ((sc0[8] + sc0[9]) + (sc0[10] + sc0[11])) + ((sc0[12] + sc0[13]) + (sc0[14] + sc0[15]));
    float s2 = ((sc1[0] + sc1[1]) + (sc1[2] + sc1[3])) + ((sc1[4] + sc1[5]) + (sc1[6] + sc1[7]));
    float s3 = ((sc1[8] + sc1[9]) + (sc1[10] + sc1[11])) + ((sc1[12] + sc1[13]) + (sc1[14] + sc1[15]));
    float rsum = (s0 + s1) + (s2 + s3);
    rsum += __shfl_xor(rsum, 32);
    ls += rsum;

#pragma unroll
    for (int t2 = 0; t2 < 2; ++t2) {
      const f32x16& p = t2 ? sc1 : sc0;
      uint32 c0 = cvtpk_bf16(p[0], p[1]),   c1 = cvtpk_bf16(p[2], p[3]);
      uint32 c2 = cvtpk_bf16(p[4], p[5]),   c3 = cvtpk_bf16(p[6], p[7]);
      uint32 c4 = cvtpk_bf16(p[8], p[9]),   c5 = cvtpk_bf16(p[10], p[11]);
      uint32 c6 = cvtpk_bf16(p[12], p[13]), c7 = cvtpk_bf16(p[14], p[15]);
      uint32 za = half ? c0 : c2, zb = half ? c1 : c3;
      uint32 zc = half ? c4 : c6, zd = half ? c5 : c7;
      za = __shfl_xor((int)za, 32); zb = __shfl_xor((int)zb, 32);
      zc = __shfl_xor((int)zc, 32); zd = __shfl_xor((int)zd, 32);
      uint4 v0, v1;
      if (half == 0) { v0 = (uint4){c0, c1, za, zb}; v1 = (uint4){c4, c5, zc, zd}; }
      else           { v0 = (uint4){za, zb, c2, c3}; v1 = (uint4){zc, zd, c6, c7}; }
      pa[2 * t2 + 0] = __builtin_bit_cast(bh8, v0);
      pa[2 * t2 + 1] = __builtin_bit_cast(bh8, v1);
    }
  };

  // ---- tile 0: QK + softmax only (no PV yet) ----
  {
    asm volatile("s_waitcnt vmcnt(0)" ::: "memory");
    __builtin_amdgcn_s_barrier();
    if (nt > 1) { stageK(Kb1, kb0 + 64); stageV(Vn, kb0 + 64); }
    char* Kl = Kb0;
    f32x16 sc0, sc1;
#pragma unroll
    for (int i = 0; i < 16; ++i) { sc0[i] = 0.f; sc1[i] = 0.f; }
#pragma unroll
    for (int t = 0; t < 16; ++t) {
      bh8 kf0 = *(const bh8*)(Kl + r0 * 512 + (((2 * t + half) ^ (r0 & 7)) * 16));
      bh8 kf1 = *(const bh8*)(Kl + r1 * 512 + (((2 * t + half) ^ (r1 & 7)) * 16));
      sc0 = __builtin_amdgcn_mfma_f32_32x32x16_bf16(kf0, qf[t], sc0, 0, 0, 0);
      sc1 = __builtin_amdgcn_mfma_f32_32x32x16_bf16(kf1, qf[t], sc1, 0, 0, 0);
    }
    softmax_pa(sc0, sc1);
    char* tmp = Vp; Vp = Vc; Vc = Vn; Vn = tmp;
  }

  // ---- tiles 1..nt-1: merged QK(kt) + PV(kt-1) ----
  for (int kt = 1; kt < nt; ++kt) {
    asm volatile("s_waitcnt vmcnt(0)" ::: "memory");
    __builtin_amdgcn_s_barrier();
    if (kt + 1 < nt) {
      stageK((kt & 1) ? Kb0 : Kb1, kb0 + (kt + 1) * 64);
      stageV(Vn, kb0 + (kt + 1) * 64);
    }
    char* Kl = (kt & 1) ? Kb1 : Kb0;
    f32x16 sc0, sc1;
#pragma unroll
    for (int i = 0; i < 16; ++i) { sc0[i] = 0.f; sc1[i] = 0.f; }
#pragma unroll
    for (int t = 0; t < 16; ++t) {
      bh8 kf0 = *(const bh8*)(Kl + r0 * 512 + (((2 * t + half) ^ (r0 & 7)) * 16));
      bh8 kf1 = *(const bh8*)(Kl + r1 * 512 + (((2 * t + half) ^ (r1 & 7)) * 16));
      sc0 = __builtin_amdgcn_mfma_f32_32x32x16_bf16(kf0, qf[t], sc0, 0, 0, 0);
      sc1 = __builtin_amdgcn_mfma_f32_32x32x16_bf16(kf1, qf[t], sc1, 0, 0, 0);
      // PV(kt-1): 2 independent MFMAs per step fill QK chain bubbles
      int dt = t >> 1, ksb = (t & 1) * 2;
      int rv = dt * 32 + col;
      bh8 vfa = *(const bh8*)(Vp + rv * 128 + (((2 * ksb + half) ^ (rv & 7)) * 16));
      o[dt] = __builtin_amdgcn_mfma_f32_32x32x16_bf16(pa[ksb], vfa, o[dt], 0, 0, 0);
      bh8 vfb = *(const bh8*)(Vp + rv * 128 + (((2 * ksb + 2 + half) ^ (rv & 7)) * 16));
      o[dt] = __builtin_amdgcn_mfma_f32_32x32x16_bf16(pa[ksb + 1], vfb, o[dt], 0, 0, 0);
    }
    softmax_pa(sc0, sc1);
    char* tmp = Vp; Vp = Vc; Vc = Vn; Vn = tmp;
  }

  // ---- epilogue: PV for the last tile (V(nt-1) is at Vp after rotation) ----
#pragma unroll
  for (int dt = 0; dt < 8; ++dt) {
    int rv = dt * 32 + col;
#pragma unroll
    for (int ks = 0; ks < 4; ++ks) {
      bh8 vf = *(const bh8*)(Vp + rv * 128 + (((2 * ks + half) ^ (rv & 7)) * 16));
      o[dt] = __builtin_amdgcn_mfma_f32_32x32x16_bf16(pa[ks], vf, o[dt], 0, 0, 0);
    }
  }

  // ---- partials: packed half2, plain coalesced stores.
  // u32 index (s*8192+row)*128 + j*32 + col holds (lo: d=64j+col, hi: d=64j+32+col)
#pragma unroll
  for (int i = 0; i < 16; ++i) {
    int qr = (i & 3) + 8 * (i >> 2) + 4 * half;
    uint32* ob = Op + ((size_t)s * 8192 + qrow0 + qr) * 128 + col;
#pragma unroll
    for (int j = 0; j < 4; ++j) {
      h16x2 hp = __builtin_amdgcn_cvt_pkrtz(o[2 * j][i], o[2 * j + 1][i]);
      ob[j * 32] = __builtin_bit_cast(uint32, hp);
    }
  }
  if (l < 32) {
    mp[(size_t)s * 8192 + qrow0 + col] = m;
    lp[(size_t)s * 8192 + qrow0 + col] = ls;
  }
}

// ---------------------------------------------------------------------------
// Split-K combine. Block = (t, j: 64-d group, phalf: 128 p-rows); grid (32,4,2).
// Uses BOTH halves of every u32 (full 128B-line utilization, no amplification).
__global__ __launch_bounds__(256) void k_combine(
    const uint32* __restrict__ Op, const float* __restrict__ mp,
    const float* __restrict__ lp, float* __restrict__ out, int S) {
  __shared__ float wsc[16 * 128];
  __shared__ float lt[64 * 129];
  int t = blockIdx.x, j = blockIdx.y, ph = blockIdx.z, tid = threadIdx.x;
  int n0 = t * 256 + ph * 128;

  if (tid < 128) {
    int n = n0 + tid;
    float mt = -INFINITY;
#pragma unroll 16
    for (int s = 0; s < 16; ++s)
      if (s < S) mt = fmaxf(mt, mp[(size_t)s * 8192 + n]);
    float den = 0.f;
#pragma unroll 16
    for (int s = 0; s < 16; ++s)
      if (s < S) den += exp2f(mp[(size_t)s * 8192 + n] - mt) * lp[(size_t)s * 8192 + n];
    float inv = 1.0f / den;
#pragma unroll 16
    for (int s = 0; s < 16; ++s)
      if (s < S) wsc[s * 128 + tid] = exp2f(mp[(size_t)s * 8192 + n] - mt) * inv;
  }
  __syncthreads();

  int c = tid & 31, rg = tid >> 5;   // 32 u32-cols x 8 rows per pass
  for (int pass = 0; pass < 16; ++pass) {
    int p = pass * 8 + rg;           // row within this 128-row half
    int n = n0 + p;
    float alo = 0.f, ahi = 0.f;
#pragma unroll 16
    for (int s = 0; s < 16; ++s)
      if (s < S) {
        uint32 v = Op[((size_t)s * 8192 + n) * 128 + j * 32 + c];
        h16x2 h2 = __builtin_bit_cast(h16x2, v);
        float ws = wsc[s * 128 + p];
        alo += ws * (float)h2[0];
        ahi += ws * (float)h2[1];
      }
    lt[c * 129 + p] = alo;            // d = 64j + c
    lt[(c + 32) * 129 + p] = ahi;     // d = 64j + 32 + c
  }
  __syncthreads();

  int dd = tid >> 2, pq = tid & 3;    // 64 d-rows x 4 p-quads(32 each)
  float* ob = out + (size_t)t * 65536 + (size_t)(j * 64 + dd) * 256 + ph * 128 + pq * 32;
  const float* lr = &lt[dd * 129 + pq * 32];
#pragma unroll
  for (int i = 0; i < 8; ++i) {
    float4 v;
    v.x = lr[4 * i + 0]; v.y = lr[4 * i + 1]; v.z = lr[4 * i + 2]; v.w = lr[4 * i + 3];
    *(float4*)(ob + 4 * i) = v;
  }
}

// ---------------------------------------------------------------------------
extern "C" void kernel_launch(void* const* d_in, const int* in_sizes, int n_in,
                              void* d_out, int out_size, void* d_ws, size_t ws_size,
                              hipStream_t stream) {
  const float* hidden = (const float*)d_in[0];
  const float* Wq = (const float*)d_in[1];
  const float* Wk = (const float*)d_in[2];
  const float* Wv = (const float*)d_in[3];
  float* out = (float*)d_out;
  char* ws = (char*)d_ws;

  // Layout: [xb 4MB (reused for m/l by attn)] [wt 384KB] [q 4MB] [k 4MB] [vt 4MB]
  //         [Op packed-half2 S*4MB]
  const size_t off_x  = 0;
  const size_t off_wt = 4ull << 20;
  const size_t off_q  = off_wt + 3ull * 131072;
  const size_t off_k  = off_q + 8192ull * 256 * 2;
  const size_t off_vt = off_k + 8192ull * 256 * 2;
  const size_t off_O  = off_vt + 8192ull * 256 * 2;

  int S = 8, shift = 3;
  {
    auto need = [&](int s) { return off_O + (size_t)s * 8192 * 128 * 4; };
    if (ws_size < need(8)) { S = 4; shift = 2; }
    if (ws_size < need(4)) { S = 2; shift = 1; }
  }

  unsigned short* xb  = (unsigned short*)(ws + off_x);
  unsigned short* wt  = (unsigned short*)(ws + off_wt);
  unsigned short* qb  = (unsigned short*)(ws + off_q);
  unsigned short* kb  = (unsigned short*)(ws + off_k);
  unsigned short* vtb = (unsigned short*)(ws + off_vt);
  uint32* Op = (uint32*)(ws + off_O);
  float* mp = (float*)(ws + off_x);                  // xb dead after k_gemm
  float* lp = (float*)(ws + off_x + (2ull << 20));
  int KS = 8192 / S;

  const int attn_lds = 163840;   // K dbuf 64KB + V tbuf 96KB = 160KB; 1 block/CU
  (void)hipFuncSetAttribute((const void*)k_attn, hipFuncAttributeMaxDynamicSharedMemorySize,
                            attn_lds);

  k_transpose<<<dim3(35, 16), dim3(256), 0, stream>>>(hidden, Wq, Wk, Wv, xb, wt);
  k_gemm<<<dim3(64, 2, 3), dim3(256), 0, stream>>>(xb, wt, qb, kb, vtb);
  k_attn<<<dim3(32 * S), dim3(512), attn_lds, stream>>>(qb, kb, vtb, Op, mp, lp, S, shift, KS);
  k_combine<<<dim3(32, 4, 2), dim3(256), 0, stream>>>(Op, mp, lp, out, S);
}

// Round 17
// 143.737 us; speedup vs baseline: 1.1465x; 1.1465x over previous
//
#include <hip/hip_runtime.h>
#include <stdint.h>

typedef __attribute__((ext_vector_type(8))) short bh8;     // 8 bf16 (MFMA A/B frag)
typedef __attribute__((ext_vector_type(4))) float f32x4;
typedef __attribute__((ext_vector_type(16))) float f32x16; // 32x32 MFMA C/D frag
typedef __attribute__((ext_vector_type(2))) __fp16 h16x2;  // packed half2 (native)
typedef unsigned int uint32;

__device__ __forceinline__ unsigned short f2bf(float f) {
  uint32 u = __builtin_bit_cast(uint32, f);
  u += 0x7fffu + ((u >> 16) & 1u);   // RNE
  return (unsigned short)(u >> 16);
}

__device__ __forceinline__ uint32 cvtpk_bf16(float lo, float hi) {
  uint32 r;
  asm("v_cvt_pk_bf16_f32 %0, %1, %2" : "=v"(r) : "v"(lo), "v"(hi));
  return r;
}

__device__ __forceinline__ float exp2_hw(float x) {
  float r;
  asm("v_exp_f32 %0, %1" : "=v"(r) : "v"(x));
  return r;
}

__device__ __forceinline__ float max3f(float a, float b, float c) {
  return fmaxf(fmaxf(a, b), c);   // clang fuses to v_max3_f32
}

// global -> LDS direct (16B/lane). LDS dest linear; swizzle via GLOBAL source addr.
__device__ __forceinline__ void lds_load16(const void* g, void* l) {
  auto gp = (const __attribute__((address_space(1))) uint32*)(uintptr_t)(g);
  auto lp = (__attribute__((address_space(3))) uint32*)(uintptr_t)(l);
  __builtin_amdgcn_global_load_lds(gp, lp, 16, 0, 0);
}

// ---------------------------------------------------------------------------
// Transpose hidden (t,c,p) -> x_bf16[n=t*256+p][c], and W (c,d) -> Wt_bf16[d][c].
// Wq gets 1/sqrt(256) * log2(e) folded in (softmax runs in exp2 domain).
__global__ __launch_bounds__(256) void k_transpose(
    const float* __restrict__ hidden, const float* __restrict__ Wq,
    const float* __restrict__ Wk, const float* __restrict__ Wv,
    unsigned short* __restrict__ xb, unsigned short* __restrict__ wt) {
  int bid = blockIdx.x, c0 = blockIdx.y * 16, tid = threadIdx.x;
  const float* in; unsigned short* out; float scale = 1.0f;
  if (bid < 32) { in = hidden + (size_t)bid * 65536; out = xb + (size_t)bid * 65536; }
  else {
    int j = bid - 32;
    in = (j == 0) ? Wq : (j == 1 ? Wk : Wv);
    out = wt + (size_t)j * 65536;
    if (j == 0) scale = 0.0625f * 1.4426950408889634f;   // 1/sqrt(256) * log2(e)
  }
  __shared__ uint32 lt[256 * 9];
  uint32 pk[8];
#pragma unroll
  for (int i = 0; i < 8; ++i) {
    float a = in[(size_t)(c0 + 2 * i) * 256 + tid] * scale;      // coalesced along p
    float b = in[(size_t)(c0 + 2 * i + 1) * 256 + tid] * scale;
    pk[i] = (uint32)f2bf(a) | ((uint32)f2bf(b) << 16);
  }
#pragma unroll
  for (int i = 0; i < 8; ++i) lt[tid * 9 + i] = pk[i];
  __syncthreads();
  int q2 = tid & 1;
#pragma unroll
  for (int rr = 0; rr < 2; ++rr) {
    int r = rr * 128 + (tid >> 1);
    uint4 v;
    v.x = lt[r * 9 + q2 * 4 + 0]; v.y = lt[r * 9 + q2 * 4 + 1];
    v.z = lt[r * 9 + q2 * 4 + 2]; v.w = lt[r * 9 + q2 * 4 + 3];
    *(uint4*)(out + (size_t)r * 256 + c0 + q2 * 8) = v;          // 16B coalesced
  }
}

// ---------------------------------------------------------------------------
// GEMM: z=0: q = x*WqT_t, z=1: k = x*WkT_t (row-major [n][d]),
//       z=2: vT[d][n] = (WvT * xT)  (operand-swapped so output is d-major).
__global__ __launch_bounds__(256, 2) void k_gemm(
    const unsigned short* __restrict__ xb, const unsigned short* __restrict__ wt,
    unsigned short* __restrict__ qb, unsigned short* __restrict__ kb,
    unsigned short* __restrict__ vtb) {
  __shared__ char lds[32768];
  char* ldsA = lds; char* ldsB = lds + 16384;
  int tid = threadIdx.x, z = blockIdx.z;
  int l = tid & 63, w = tid >> 6, g = l >> 4, r15 = l & 15;
  int wr = w >> 1, wc = w & 1;
  const unsigned short *Ag, *Bg; unsigned short* out;
  int arow0, brow0; size_t ostride;
  if (z < 2) {
    Ag = xb; arow0 = blockIdx.x * 128;
    Bg = wt + (size_t)z * 65536; brow0 = blockIdx.y * 128;
    out = z ? kb : qb; ostride = 256;
  } else {
    Ag = wt + 2 * 65536; arow0 = blockIdx.y * 128;
    Bg = xb; brow0 = blockIdx.x * 128;
    out = vtb; ostride = 8192;
  }
  f32x4 acc[4][4];
#pragma unroll
  for (int i = 0; i < 4; ++i)
#pragma unroll
    for (int j = 0; j < 4; ++j) acc[i][j] = (f32x4){0.f, 0.f, 0.f, 0.f};

  for (int kk = 0; kk < 4; ++kk) {
    int c0 = kk * 64;
    __syncthreads();
#pragma unroll
    for (int p = 0; p < 4; ++p) {     // A tile [128][64] bf16, swizzled chunks
      int off = p * 4096 + tid * 16;
      int row = off >> 7, ch = (off >> 4) & 7, sc = ch ^ (row & 7);
      lds_load16((const char*)Ag + ((size_t)(arow0 + row) * 256 + c0) * 2 + sc * 16, ldsA + off);
    }
#pragma unroll
    for (int p = 0; p < 4; ++p) {     // B tile [128][64] bf16 (col-major tile), swizzled
      int off = p * 4096 + tid * 16;
      int row = off >> 7, ch = (off >> 4) & 7, sc = ch ^ (row & 7);
      lds_load16((const char*)Bg + ((size_t)(brow0 + row) * 256 + c0) * 2 + sc * 16, ldsB + off);
    }
    __syncthreads();
#pragma unroll
    for (int ks = 0; ks < 2; ++ks) {
      bh8 af[4], bfr[4];
#pragma unroll
      for (int i = 0; i < 4; ++i) {
        int rowa = wr * 64 + i * 16 + r15;
        af[i] = *(const bh8*)(ldsA + rowa * 128 + (((ks * 4 + g) ^ (rowa & 7)) * 16));
        int rowb = wc * 64 + i * 16 + r15;
        bfr[i] = *(const bh8*)(ldsB + rowb * 128 + (((ks * 4 + g) ^ (rowb & 7)) * 16));
      }
#pragma unroll
      for (int i = 0; i < 4; ++i)
#pragma unroll
        for (int j = 0; j < 4; ++j)
          acc[i][j] = __builtin_amdgcn_mfma_f32_16x16x32_bf16(af[i], bfr[j], acc[i][j], 0, 0, 0);
    }
  }
  __syncthreads();
  // bounce C (bf16) through LDS for coalesced stores
#pragma unroll
  for (int i = 0; i < 4; ++i)
#pragma unroll
    for (int j = 0; j < 4; ++j)
#pragma unroll
      for (int r = 0; r < 4; ++r) {
        int rowl = wr * 64 + i * 16 + g * 4 + r;   // C/D: row=(l>>4)*4+reg
        int coll = wc * 64 + j * 16 + r15;         //      col=l&15
        *(unsigned short*)(lds + rowl * 256 + coll * 2) = f2bf(acc[i][j][r]);
      }
  __syncthreads();
#pragma unroll
  for (int p = 0; p < 8; ++p) {
    int off = p * 4096 + tid * 16;
    int row = off >> 8, colb = off & 255;
    *(uint4*)((char*)out + ((size_t)(arow0 + row) * ostride + (size_t)brow0) * 2 + colb) =
        *(const uint4*)(lds + off);
  }
}

// ---------------------------------------------------------------------------
// Flash attention, swapped-QK^T 32x32x16 (r15 config -- best measured: 112.6us).
// 8 waves x 32 q-rows (QBLK=256), KVBLK=64 double-buffered (2x64KB LDS),
// single-barrier tile cycle; dual-chain QK; one combined defer-max softmax.
// PLATEAU NOTE (r9-r16): seven schedule variants (dbuf-vmcnt, 2blk/CU,
// setprio, trees, single-barrier, deferred-PV) all land 112-126us at
// MfmaUtil ~24% -- the structure's practical ceiling at 2 waves/SIMD
// (register-forced). Further gains need the fully co-designed T2-T5/T16
// combo which does not graft piecewise (guide: "NULL as additive graft").
__global__ __launch_bounds__(512, 2) void k_attn(
    const unsigned short* __restrict__ qg, const unsigned short* __restrict__ kg,
    const unsigned short* __restrict__ vtg, uint32* __restrict__ Op,
    float* __restrict__ mp, float* __restrict__ lp, int S, int shift, int KS) {
  extern __shared__ char smem[];
  int tid = threadIdx.x;
  int w = tid >> 6, l = tid & 63, col = l & 31, half = l >> 5;
  int bid = blockIdx.x;
  int s = bid & (S - 1);       // XCD-pinned slice
  int qb = bid >> shift;
  int qrow0 = qb * 256 + w * 32;

  int nt = KS >> 6, kb0 = s * KS;

  // stage one 64KB KV tile: 8 x lds_load16 per thread (512 threads)
  auto stage = [&](int buf, int kvb) {
    char* Kd = smem + buf * 65536;          // K [64][512B] = 32KB
    char* Vd = Kd + 32768;                  // VT [256][128B] = 32KB
#pragma unroll
    for (int p = 0; p < 4; ++p) {
      int off = p * 8192 + tid * 16;
      int row = off >> 9, ch = (off >> 4) & 31;
      lds_load16((const char*)kg + (size_t)(kvb + row) * 512 + ((ch ^ (row & 7)) * 16), Kd + off);
    }
#pragma unroll
    for (int p = 0; p < 4; ++p) {
      int off = p * 8192 + tid * 16;
      int row = off >> 7, ch = (off >> 4) & 7;
      lds_load16((const char*)vtg + (size_t)row * 16384 + (size_t)kvb * 2 + ((ch ^ (row & 7)) * 16),
                 Vd + off);
    }
  };

  stage(0, kb0);   // prologue

  // Q hoisted as B-fragments: lane's q-row = qrow0+col; 16 d-slices x 8 bf16
  bh8 qf[16];
  {
    const char* qrow = (const char*)qg + (size_t)(qrow0 + col) * 512 + half * 16;
#pragma unroll
    for (int t = 0; t < 16; ++t) qf[t] = *(const bh8*)(qrow + t * 32);
  }

  f32x16 o[8];
#pragma unroll
  for (int dt = 0; dt < 8; ++dt)
#pragma unroll
    for (int i = 0; i < 16; ++i) o[dt][i] = 0.f;
  float m = -INFINITY, ls = 0.f;

  for (int kt = 0; kt < nt; ++kt) {
    int cur = kt & 1;
    // tile kt's loads were issued a full compute-iteration ago -> no stall
    asm volatile("s_waitcnt vmcnt(0)" ::: "memory");
    __builtin_amdgcn_s_barrier();    // all waves: tile kt staged; compute(kt-1) done
    if (kt + 1 < nt) stage(cur ^ 1, kb0 + (kt + 1) * 64);
    char* Kl = smem + cur * 65536;
    char* Vl = Kl + 32768;

    // ---- dual-chain QK over both 32-row halves (independent accumulators) ----
    f32x16 sc0, sc1;
#pragma unroll
    for (int i = 0; i < 16; ++i) { sc0[i] = 0.f; sc1[i] = 0.f; }
    int r0 = col, r1 = 32 + col;
#pragma unroll
    for (int t = 0; t < 16; ++t) {
      bh8 kf0 = *(const bh8*)(Kl + r0 * 512 + (((2 * t + half) ^ (r0 & 7)) * 16));
      bh8 kf1 = *(const bh8*)(Kl + r1 * 512 + (((2 * t + half) ^ (r1 & 7)) * 16));
      sc0 = __builtin_amdgcn_mfma_f32_32x32x16_bf16(kf0, qf[t], sc0, 0, 0, 0);
      sc1 = __builtin_amdgcn_mfma_f32_32x32x16_bf16(kf1, qf[t], sc1, 0, 0, 0);
    }

    // ---- ONE softmax pass for all 64 keys (exp2 domain, defer-max) ----
    float t0 = max3f(sc0[0], sc0[1], sc0[2]);
    float t1 = max3f(sc0[3], sc0[4], sc0[5]);
    float t2 = max3f(sc0[6], sc0[7], sc0[8]);
    float t3 = max3f(sc0[9], sc0[10], sc0[11]);
    float t4 = max3f(sc0[12], sc0[13], sc0[14]);
    float rm0 = fmaxf(max3f(t0, t1, t2), max3f(t3, t4, sc0[15]));
    float u0 = max3f(sc1[0], sc1[1], sc1[2]);
    float u1 = max3f(sc1[3], sc1[4], sc1[5]);
    float u2 = max3f(sc1[6], sc1[7], sc1[8]);
    float u3 = max3f(sc1[9], sc1[10], sc1[11]);
    float u4 = max3f(sc1[12], sc1[13], sc1[14]);
    float rm1 = fmaxf(max3f(u0, u1, u2), max3f(u3, u4, sc1[15]));
    float rm = fmaxf(rm0, rm1);
    rm = fmaxf(rm, __shfl_xor(rm, 32));

    if (__any(rm > m + 6.0f)) {      // rescale path (rare: T13 defer-max)
      float mn = fmaxf(m, rm);
      float scl = exp2_hw(m - mn);
      m = mn;
      float sclb[16];
#pragma unroll
      for (int i = 0; i < 16; ++i) {
        int qs = (i & 3) + 8 * (i >> 2) + 4 * half;   // q-row held in reg i
        sclb[i] = __shfl(scl, qs);
      }
#pragma unroll
      for (int dt = 0; dt < 8; ++dt)
#pragma unroll
        for (int i = 0; i < 16; ++i) o[dt][i] *= sclb[i];
      ls *= scl;
    }
#pragma unroll
    for (int i = 0; i < 16; ++i) sc0[i] = exp2_hw(sc0[i] - m);
#pragma unroll
    for (int i = 0; i < 16; ++i) sc1[i] = exp2_hw(sc1[i] - m);
    float s0 = ((sc0[0] + sc0[1]) + (sc0[2] + sc0[3])) + ((sc0[4] + sc0[5]) + (sc0[6] + sc0[7]));
    float s1 = ((sc0[8] + sc0[9]) + (sc0[10] + sc0[11])) + ((sc0[12] + sc0[13]) + (sc0[14] + sc0[15]));
    float s2 = ((sc1[0] + sc1[1]) + (sc1[2] + sc1[3])) + ((sc1[4] + sc1[5]) + (sc1[6] + sc1[7]));
    float s3 = ((sc1[8] + sc1[9]) + (sc1[10] + sc1[11])) + ((sc1[12] + sc1[13]) + (sc1[14] + sc1[15]));
    float rsum = (s0 + s1) + (s2 + s3);
    rsum += __shfl_xor(rsum, 32);
    ls += rsum;

    // ---- P -> PV A-fragments for BOTH halves (cvt_pk + half-exchange) ----
    bh8 pa[4];
#pragma unroll
    for (int t2 = 0; t2 < 2; ++t2) {
      const f32x16& p = t2 ? sc1 : sc0;
      uint32 c0 = cvtpk_bf16(p[0], p[1]),   c1 = cvtpk_bf16(p[2], p[3]);
      uint32 c2 = cvtpk_bf16(p[4], p[5]),   c3 = cvtpk_bf16(p[6], p[7]);
      uint32 c4 = cvtpk_bf16(p[8], p[9]),   c5 = cvtpk_bf16(p[10], p[11]);
      uint32 c6 = cvtpk_bf16(p[12], p[13]), c7 = cvtpk_bf16(p[14], p[15]);
      uint32 za = half ? c0 : c2, zb = half ? c1 : c3;
      uint32 zc = half ? c4 : c6, zd = half ? c5 : c7;
      za = __shfl_xor((int)za, 32); zb = __shfl_xor((int)zb, 32);
      zc = __shfl_xor((int)zc, 32); zd = __shfl_xor((int)zd, 32);
      uint4 v0, v1;
      if (half == 0) { v0 = (uint4){c0, c1, za, zb}; v1 = (uint4){c4, c5, zc, zd}; }
      else           { v0 = (uint4){za, zb, c2, c3}; v1 = (uint4){zc, zd, c6, c7}; }
      pa[2 * t2 + 0] = __builtin_bit_cast(bh8, v0);
      pa[2 * t2 + 1] = __builtin_bit_cast(bh8, v1);
    }

    // ---- PV: O[q][dv] += P * V ; B-frag chunk = 2ks+half of VT row (8 chunks) ----
#pragma unroll
    for (int dt = 0; dt < 8; ++dt) {
      int rv = dt * 32 + col;
#pragma unroll
      for (int ks = 0; ks < 4; ++ks) {
        bh8 vf = *(const bh8*)(Vl + rv * 128 + (((2 * ks + half) ^ (rv & 7)) * 16));
        o[dt] = __builtin_amdgcn_mfma_f32_32x32x16_bf16(pa[ks], vf, o[dt], 0, 0, 0);
      }
    }
  }

  // ---- partials: packed half2, plain coalesced stores.
  // u32 index (s*8192+row)*128 + j*32 + col holds (lo: d=64j+col, hi: d=64j+32+col)
#pragma unroll
  for (int i = 0; i < 16; ++i) {
    int qr = (i & 3) + 8 * (i >> 2) + 4 * half;
    uint32* ob = Op + ((size_t)s * 8192 + qrow0 + qr) * 128 + col;
#pragma unroll
    for (int j = 0; j < 4; ++j) {
      h16x2 hp = __builtin_amdgcn_cvt_pkrtz(o[2 * j][i], o[2 * j + 1][i]);
      ob[j * 32] = __builtin_bit_cast(uint32, hp);
    }
  }
  if (l < 32) {
    mp[(size_t)s * 8192 + qrow0 + col] = m;
    lp[(size_t)s * 8192 + qrow0 + col] = ls;
  }
}

// ---------------------------------------------------------------------------
// Split-K combine. r17: ph split 2->4 => grid (32,4,4) = 512 blocks (2/CU)
// for latency hiding. Block = (t, j: 64-d group, ph: 64 p-rows).
// Uses BOTH halves of every u32 (full 128B-line utilization).
__global__ __launch_bounds__(256) void k_combine(
    const uint32* __restrict__ Op, const float* __restrict__ mp,
    const float* __restrict__ lp, float* __restrict__ out, int S) {
  __shared__ float wsc[16 * 64];
  __shared__ float lt[64 * 65];
  int t = blockIdx.x, j = blockIdx.y, ph = blockIdx.z, tid = threadIdx.x;
  int n0 = t * 256 + ph * 64;

  if (tid < 64) {
    int n = n0 + tid;
    float mt = -INFINITY;
#pragma unroll 16
    for (int s = 0; s < 16; ++s)
      if (s < S) mt = fmaxf(mt, mp[(size_t)s * 8192 + n]);
    float den = 0.f;
#pragma unroll 16
    for (int s = 0; s < 16; ++s)
      if (s < S) den += exp2f(mp[(size_t)s * 8192 + n] - mt) * lp[(size_t)s * 8192 + n];
    float inv = 1.0f / den;
#pragma unroll 16
    for (int s = 0; s < 16; ++s)
      if (s < S) wsc[s * 64 + tid] = exp2f(mp[(size_t)s * 8192 + n] - mt) * inv;
  }
  __syncthreads();

  int c = tid & 31, rg = tid >> 5;   // 32 u32-cols x 8 rows per pass
  for (int pass = 0; pass < 8; ++pass) {
    int p = pass * 8 + rg;           // row within this 64-row group
    int n = n0 + p;
    float alo = 0.f, ahi = 0.f;
#pragma unroll 16
    for (int s = 0; s < 16; ++s)
      if (s < S) {
        uint32 v = Op[((size_t)s * 8192 + n) * 128 + j * 32 + c];
        h16x2 h2 = __builtin_bit_cast(h16x2, v);
        float ws = wsc[s * 64 + p];
        alo += ws * (float)h2[0];
        ahi += ws * (float)h2[1];
      }
    lt[c * 65 + p] = alo;            // d = 64j + c
    lt[(c + 32) * 65 + p] = ahi;     // d = 64j + 32 + c
  }
  __syncthreads();

  int dd = tid >> 2, pq = tid & 3;   // 64 d-rows x 4 p-quads(16 each)
  float* ob = out + (size_t)t * 65536 + (size_t)(j * 64 + dd) * 256 + ph * 64 + pq * 16;
  const float* lr = &lt[dd * 65 + pq * 16];
#pragma unroll
  for (int i = 0; i < 4; ++i) {
    float4 v;
    v.x = lr[4 * i + 0]; v.y = lr[4 * i + 1]; v.z = lr[4 * i + 2]; v.w = lr[4 * i + 3];
    *(float4*)(ob + 4 * i) = v;
  }
}

// ---------------------------------------------------------------------------
extern "C" void kernel_launch(void* const* d_in, const int* in_sizes, int n_in,
                              void* d_out, int out_size, void* d_ws, size_t ws_size,
                              hipStream_t stream) {
  const float* hidden = (const float*)d_in[0];
  const float* Wq = (const float*)d_in[1];
  const float* Wk = (const float*)d_in[2];
  const float* Wv = (const float*)d_in[3];
  float* out = (float*)d_out;
  char* ws = (char*)d_ws;

  // Layout: [xb 4MB (reused for m/l by attn)] [wt 384KB] [q 4MB] [k 4MB] [vt 4MB]
  //         [Op packed-half2 S*4MB]
  const size_t off_x  = 0;
  const size_t off_wt = 4ull << 20;
  const size_t off_q  = off_wt + 3ull * 131072;
  const size_t off_k  = off_q + 8192ull * 256 * 2;
  const size_t off_vt = off_k + 8192ull * 256 * 2;
  const size_t off_O  = off_vt + 8192ull * 256 * 2;

  int S = 8, shift = 3;
  {
    auto need = [&](int s) { return off_O + (size_t)s * 8192 * 128 * 4; };
    if (ws_size < need(8)) { S = 4; shift = 2; }
    if (ws_size < need(4)) { S = 2; shift = 1; }
  }

  unsigned short* xb  = (unsigned short*)(ws + off_x);
  unsigned short* wt  = (unsigned short*)(ws + off_wt);
  unsigned short* qb  = (unsigned short*)(ws + off_q);
  unsigned short* kb  = (unsigned short*)(ws + off_k);
  unsigned short* vtb = (unsigned short*)(ws + off_vt);
  uint32* Op = (uint32*)(ws + off_O);
  float* mp = (float*)(ws + off_x);                  // xb dead after k_gemm
  float* lp = (float*)(ws + off_x + (2ull << 20));
  int KS = 8192 / S;

  const int attn_lds = 131072;   // 2 x 64KB double-buffered tiles; 1 block/CU
  (void)hipFuncSetAttribute((const void*)k_attn, hipFuncAttributeMaxDynamicSharedMemorySize,
                            attn_lds);

  k_transpose<<<dim3(35, 16), dim3(256), 0, stream>>>(hidden, Wq, Wk, Wv, xb, wt);
  k_gemm<<<dim3(64, 2, 3), dim3(256), 0, stream>>>(xb, wt, qb, kb, vtb);
  k_attn<<<dim3(32 * S), dim3(512), attn_lds, stream>>>(qb, kb, vtb, Op, mp, lp, S, shift, KS);
  k_combine<<<dim3(32, 4, 4), dim3(256), 0, stream>>>(Op, mp, lp, out, S);
}